// Round 13
// baseline (374.555 us; speedup 1.0000x reference)
//
#include <hip/hip_runtime.h>
#include <math.h>

#define NROWS 262144
#define DDIM  1024
#define EEXP  64
#define NDOCS 1024
#define BM    128
#define HB    64            // hist/scatter blocks
#define RPB   (NROWS / HB)  // rows per hist/scatter block
#define NGEMM (NROWS / BM)  // 2048

typedef __attribute__((ext_vector_type(8)))  __bf16 bf16x8;
typedef __attribute__((ext_vector_type(16))) float  f32x16;
typedef unsigned short ushort_t;
typedef unsigned int   uint_t;

// ws layout:
//   Wf          ushort[32*8*64*8]   (256 KB fragment-major W, hi+lo)
//   hist_slices int[HB*NDOCS]
//   sorted_rows int[NROWS]
//   offsets     int[NDOCS+1]
//   cursor      int[NDOCS]
//   pen_sum f32, uniq f32, done_count int

// ---- kernel 1: convw (blocks 0..511) + per-block hist (blocks 512..575) ----
__global__ __launch_bounds__(256) void conv_hist_kernel(const float* __restrict__ Wg,
                                                        ushort_t* __restrict__ Wf,
                                                        const int* __restrict__ idx,
                                                        int* __restrict__ hist_slices) {
    if (blockIdx.x < 512) {
        const int i = blockIdx.x * 256 + threadIdx.x;   // 0 .. 131071
        const int j = i & 7;
        const int l = (i >> 3) & 63;
        const int f = (i >> 9) & 7;
        const int T = i >> 12;
        const int cl = l & 31;
        const int hi = l >> 5;
        const int e  = cl + 32 * ((f >> 1) & 1);
        const int k  = T * 32 + 16 * (f & 1) + 8 * hi + j;
        const float wv = Wg[e * DDIM + k];
        const uint_t b = __float_as_uint(wv);
        ushort_t out;
        if (f < 4) {
            out = (ushort_t)(b >> 16);
        } else {
            const float lov = wv - __uint_as_float(b & 0xFFFF0000u);
            out = (ushort_t)(__float_as_uint(lov) >> 16);
        }
        Wf[i] = out;
    } else {
        __shared__ int lh[NDOCS];
        const int bh = blockIdx.x - 512;
        const int t  = threadIdx.x;
        for (int i = t; i < NDOCS; i += 256) lh[i] = 0;
        __syncthreads();
        const int base = bh * RPB;
        for (int i = t; i < RPB; i += 256) atomicAdd(&lh[idx[base + i]], 1);
        __syncthreads();
        for (int i = t; i < NDOCS; i += 256) hist_slices[bh * NDOCS + i] = lh[i];
    }
}

// ---- kernel 2: reduce slices -> scan -> offsets/cursor; zero scalars ----
__global__ __launch_bounds__(1024) void scan_kernel(const int* __restrict__ hist_slices,
                                                    int* __restrict__ offsets,
                                                    int* __restrict__ cursor,
                                                    float* __restrict__ pen_sum,
                                                    float* __restrict__ uniq,
                                                    int* __restrict__ done_count) {
    __shared__ int sbuf[NDOCS];
    const int t = threadIdx.x;
    int my = 0;
    #pragma unroll 4
    for (int b = 0; b < HB; ++b) my += hist_slices[b * NDOCS + t];
    sbuf[t] = my;
    __syncthreads();
    for (int off = 1; off < NDOCS; off <<= 1) {
        int add = (t >= off) ? sbuf[t - off] : 0;
        __syncthreads();
        sbuf[t] += add;
        __syncthreads();
    }
    const int excl = sbuf[t] - my;
    offsets[t] = excl;
    cursor[t]  = excl;
    if (t == NDOCS - 1) offsets[NDOCS] = sbuf[t];
    if (t == 0) { pen_sum[0] = 0.0f; uniq[0] = 0.0f; done_count[0] = 0; }
}

__device__ __forceinline__ void gl2lds16(const float* g, float* l) {
    __builtin_amdgcn_global_load_lds(
        (const __attribute__((address_space(1))) void*)g,
        (__attribute__((address_space(3))) void*)l,
        16, 0, 0);
}

#define VMCNT(N)  asm volatile("s_waitcnt vmcnt(" #N ")" ::: "memory")

// ---- kernel 3: barrier-free gemm+softmax (blocks 0..2047) + scatter (2048..2111) ----
// 512 B/row granule: 128-k supers (8 total), per-wave 16 KB buffer x2 (128 KB
// LDS, 1 block/CU). W frag-major from L2 through FOUR named reg sets (w0..w3).
// Per-wave counted vmcnt only; zero barriers; per-wave k-phase rotation mod 8.
struct WT { bf16x8 h00, h01, h10, h11, m00, m01, m10, m11; };

__global__ __launch_bounds__(256, 1) void gemm_scatter_kernel(
    const float*    __restrict__ x,
    const ushort_t* __restrict__ Wf,
    const int*      __restrict__ idx,
    int*            __restrict__ cursor,
    int*            __restrict__ sorted_rows,
    float*          __restrict__ w_out)
{
    __shared__ float xs[2][16384];   // 128 KB: 2 bufs x (4 waves x 4096 floats private)

    if (blockIdx.x >= NGEMM) {
        // ---- scatter: block-range reservation, <=NDOCS global atomics ----
        int* lh    = (int*)&xs[0][0];
        int* lbase = lh + NDOCS;
        int* lc    = lbase + NDOCS;
        const int bh = blockIdx.x - NGEMM;
        const int t  = threadIdx.x;
        for (int i = t; i < NDOCS; i += 256) { lh[i] = 0; lc[i] = 0; }
        __syncthreads();
        const int base = bh * RPB;
        for (int i = t; i < RPB; i += 256) atomicAdd(&lh[idx[base + i]], 1);
        __syncthreads();
        for (int i = t; i < NDOCS; i += 256) {
            const int c = lh[i];
            if (c) lbase[i] = atomicAdd(&cursor[i], c);
        }
        __syncthreads();
        for (int i = t; i < RPB; i += 256) {
            const int r = base + i;
            const int d = idx[r];
            const int p = atomicAdd(&lc[d], 1);
            sorted_rows[lbase[d] + p] = r;
        }
        return;
    }

    const int t   = threadIdx.x;
    const int w   = t >> 6;
    const int l   = t & 63;
    const int cl  = l & 31;     // A-row-in-wave-tile / B-col / D-col
    const int hi  = l >> 5;     // k-half selector
    const size_t br = (size_t)blockIdx.x * BM;

    f32x16 acc0 = {};
    f32x16 acc1 = {};
    WT w0, w1, w2, w3;

    union u8b { uint_t u[4]; bf16x8 v; };

#define LOAD_WF(DST, T2) do {                                                          \
        const ushort_t* p_ = Wf + ((size_t)(T2) * 8 * 64 + l) * 8;                     \
        DST.h00 = *(const bf16x8*)(p_ + 0 * 512);                                      \
        DST.h01 = *(const bf16x8*)(p_ + 1 * 512);                                      \
        DST.h10 = *(const bf16x8*)(p_ + 2 * 512);                                      \
        DST.h11 = *(const bf16x8*)(p_ + 3 * 512);                                      \
        DST.m00 = *(const bf16x8*)(p_ + 4 * 512);                                      \
        DST.m01 = *(const bf16x8*)(p_ + 5 * 512);                                      \
        DST.m10 = *(const bf16x8*)(p_ + 6 * 512);                                      \
        DST.m11 = *(const bf16x8*)(p_ + 7 * 512);                                      \
    } while (0)

// Stage one 128-k super (512 B/row) for this wave: 16 gl2lds, each 2 rows x 512 B.
// Row r base (floats) = (r>>1)*256 + (r&1)*128; 16B-unit u holds src unit u^(r&15)
// (pre-swizzled global source; linear LDS dest per rule both-sides-or-neither).
#define STAGE_X2(BUF, SUP) do {                                                        \
        float* xb_ = &xs[BUF][w * 4096];                                               \
        _Pragma("unroll")                                                              \
        for (int i_ = 0; i_ < 16; ++i_) {                                              \
            const int row_ = i_ * 2 + (l >> 5);                                        \
            const int u_   = (l & 31) ^ (row_ & 15);                                   \
            const float* gp_ = x + (br + w * 32 + row_) * DDIM + (SUP) * 128 + u_ * 4; \
            gl2lds16(gp_, xb_ + i_ * 256);                                             \
        } } while (0)

#define SPLIT8(A, B, AH, AL) do {                                                      \
        const float av_[8] = {A.x, A.y, A.z, A.w, B.x, B.y, B.z, B.w};                 \
        _Pragma("unroll")                                                              \
        for (int p_ = 0; p_ < 4; ++p_) {                                               \
            const uint_t b0_ = __float_as_uint(av_[2 * p_]);                           \
            const uint_t b1_ = __float_as_uint(av_[2 * p_ + 1]);                       \
            AH.u[p_] = (b0_ >> 16) | (b1_ & 0xFFFF0000u);                              \
            const float l0_ = av_[2 * p_]     - __uint_as_float(b0_ & 0xFFFF0000u);    \
            const float l1_ = av_[2 * p_ + 1] - __uint_as_float(b1_ & 0xFFFF0000u);    \
            AL.u[p_] = (__float_as_uint(l0_) >> 16) | (__float_as_uint(l1_) & 0xFFFF0000u); \
        } } while (0)

// Compute 32-k tile TT (0..3) of buffer BUF with W set WV.
#define COMPUTE(BUF, TT, WV) do {                                                      \
        const float* xb_ = &xs[BUF][w * 4096];                                         \
        const int blk_ = (cl >> 1) * 256 + (cl & 1) * 128;                             \
        const int ku_  = (TT) * 8 + hi * 2;                                            \
        const int sw_  = cl & 15;                                                      \
        const float4 a0_ = *(const float4*)&xb_[blk_ + (((ku_ + 0) ^ sw_) * 4)];       \
        const float4 a1_ = *(const float4*)&xb_[blk_ + (((ku_ + 1) ^ sw_) * 4)];       \
        const float4 a2_ = *(const float4*)&xb_[blk_ + (((ku_ + 4) ^ sw_) * 4)];       \
        const float4 a3_ = *(const float4*)&xb_[blk_ + (((ku_ + 5) ^ sw_) * 4)];       \
        u8b ah0, al0, ah1, al1;                                                        \
        SPLIT8(a0_, a1_, ah0, al0);                                                    \
        SPLIT8(a2_, a3_, ah1, al1);                                                    \
        acc0 = __builtin_amdgcn_mfma_f32_32x32x16_bf16(ah0.v, WV.h00, acc0, 0, 0, 0);  \
        acc1 = __builtin_amdgcn_mfma_f32_32x32x16_bf16(ah0.v, WV.h10, acc1, 0, 0, 0);  \
        acc0 = __builtin_amdgcn_mfma_f32_32x32x16_bf16(ah0.v, WV.m00, acc0, 0, 0, 0);  \
        acc1 = __builtin_amdgcn_mfma_f32_32x32x16_bf16(ah0.v, WV.m10, acc1, 0, 0, 0);  \
        acc0 = __builtin_amdgcn_mfma_f32_32x32x16_bf16(al0.v, WV.h00, acc0, 0, 0, 0);  \
        acc1 = __builtin_amdgcn_mfma_f32_32x32x16_bf16(al0.v, WV.h10, acc1, 0, 0, 0);  \
        acc0 = __builtin_amdgcn_mfma_f32_32x32x16_bf16(ah1.v, WV.h01, acc0, 0, 0, 0);  \
        acc1 = __builtin_amdgcn_mfma_f32_32x32x16_bf16(ah1.v, WV.h11, acc1, 0, 0, 0);  \
        acc0 = __builtin_amdgcn_mfma_f32_32x32x16_bf16(ah1.v, WV.m01, acc0, 0, 0, 0);  \
        acc1 = __builtin_amdgcn_mfma_f32_32x32x16_bf16(ah1.v, WV.m11, acc1, 0, 0, 0);  \
        acc0 = __builtin_amdgcn_mfma_f32_32x32x16_bf16(al1.v, WV.h01, acc0, 0, 0, 0);  \
        acc1 = __builtin_amdgcn_mfma_f32_32x32x16_bf16(al1.v, WV.h11, acc1, 0, 0, 0);  \
    } while (0)

    // Per-wave k-phase rotation over 8 supers.
    const int s0 = ((int)blockIdx.x * 5 + w) & 7;

    // ---- prologue: X(s0)->buf0 [16], w0(4*s0) [8]  => outstanding [X 16, w0 8] ----
    STAGE_X2(0, s0);
    LOAD_WF(w0, 4 * s0);

    // ---- steady supers S = 0..6 ----
    #pragma unroll 1
    for (int S = 0; S < 7; ++S) {
        const int cb   = S & 1;
        const int scur = (s0 + S) & 7;
        const int snxt = (s0 + S + 1) & 7;
        LOAD_WF(w1, 4 * scur + 1);
        LOAD_WF(w2, 4 * scur + 2);
        LOAD_WF(w3, 4 * scur + 3);
        VMCNT(24);                 // keep [w1,w2,w3]: X(S) + w0 landed
        COMPUTE(cb, 0, w0);
        STAGE_X2(cb ^ 1, snxt);    // 16 loads, stay in flight ~3 phases
        VMCNT(32);                 // keep [w2,w3,X']: w1 landed
        COMPUTE(cb, 1, w1);
        VMCNT(24);                 // keep [w3,X']: w2 landed
        COMPUTE(cb, 2, w2);
        LOAD_WF(w0, 4 * snxt);     // next super's first W set
        VMCNT(24);                 // keep [X',w0]: w3 landed
        COMPUTE(cb, 3, w3);
    }
    // ---- last super (buf 1): entry [X 16, w0 8]; no further x ----
    {
        const int slast = (s0 + 7) & 7;
        LOAD_WF(w1, 4 * slast + 1);
        LOAD_WF(w2, 4 * slast + 2);
        LOAD_WF(w3, 4 * slast + 3);
        VMCNT(24);                 // X(last) + w0 landed
        COMPUTE(1, 0, w0);
        VMCNT(16);
        COMPUTE(1, 1, w1);
        VMCNT(8);
        COMPUTE(1, 2, w2);
        VMCNT(0);
        COMPUTE(1, 3, w3);
    }

    // In-register softmax. D-layout: col = lane&31, row = (r&3) + 8*(r>>2) + 4*hi.
    const size_t orow_base = br + (size_t)w * 32;
    #pragma unroll
    for (int r = 0; r < 16; ++r) {
        const int row = (r & 3) + 8 * (r >> 2) + 4 * hi;
        const float v0 = acc0[r];
        const float v1 = acc1[r];
        float m = fmaxf(v0, v1);
        m = fmaxf(m, __shfl_xor(m, 1));
        m = fmaxf(m, __shfl_xor(m, 2));
        m = fmaxf(m, __shfl_xor(m, 4));
        m = fmaxf(m, __shfl_xor(m, 8));
        m = fmaxf(m, __shfl_xor(m, 16));
        const float e0 = __expf(v0 - m);
        const float e1 = __expf(v1 - m);
        float s = e0 + e1;
        s += __shfl_xor(s, 1);
        s += __shfl_xor(s, 2);
        s += __shfl_xor(s, 4);
        s += __shfl_xor(s, 8);
        s += __shfl_xor(s, 16);
        const float inv = 1.0f / s;
        float* wo = w_out + (orow_base + row) * EEXP;
        wo[cl]      = e0 * inv;
        wo[32 + cl] = e1 * inv;
    }
#undef LOAD_WF
#undef STAGE_X2
#undef SPLIT8
#undef COMPUTE
}

// ---- kernel 4: segsum + last-block finalize ----
__global__ __launch_bounds__(256) void segsum_final_kernel(
    const float* __restrict__ w,
    const int*   __restrict__ sorted_rows,
    const int*   __restrict__ offsets,
    float*       __restrict__ pen_sum,
    float*       __restrict__ uniq,
    int*         __restrict__ done_count,
    float*       __restrict__ pen_out)
{
    __shared__ int rows_s[512];
    __shared__ float ls1[4][64], ls2[4][64];

    const int d  = blockIdx.x;
    const int t  = threadIdx.x;
    const int e  = t & 63;
    const int rg = t >> 6;
    const int start = offsets[d];
    const int end   = offsets[d + 1];
    const int n     = end - start;

    for (int i = t; i < n && i < 512; i += 256) rows_s[i] = sorted_rows[start + i];
    __syncthreads();

    float s1 = 0.0f, s2 = 0.0f;
    for (int i = rg; i < n; i += 4) {
        const int row = (i < 512) ? rows_s[i] : sorted_rows[start + i];
        const float v = w[(size_t)row * EEXP + e];
        s1 += v;
        s2 += v * v;
    }

    ls1[rg][e] = s1;
    ls2[rg][e] = s2;
    __syncthreads();

    if (t < 64) {
        const float a = ls1[0][e] + ls1[1][e] + ls1[2][e] + ls1[3][e];
        const float b = ls2[0][e] + ls2[1][e] + ls2[2][e] + ls2[3][e];
        const float safe = fmaxf((float)n, 1.0f);
        float contrib = b - a * a / safe;
        #pragma unroll
        for (int off = 32; off > 0; off >>= 1)
            contrib += __shfl_down(contrib, off);
        if (e == 0) {
            if (n > 1) atomicAdd(pen_sum, contrib / (safe * (float)EEXP));
            if (n > 0) atomicAdd(uniq, 1.0f);
        }
    }
    __syncthreads();
    if (t == 0) {
        __threadfence();
        const int prev = atomicAdd(done_count, 1);
        if (prev == NDOCS - 1) {
            __threadfence();
            pen_out[0] = pen_sum[0] / uniq[0];
        }
    }
}

extern "C" void kernel_launch(void* const* d_in, const int* in_sizes, int n_in,
                              void* d_out, int out_size, void* d_ws, size_t ws_size,
                              hipStream_t stream) {
    const float* x   = (const float*)d_in[0];
    const int*   idx = (const int*)d_in[1];
    const float* Wg  = (const float*)d_in[2];

    float* out   = (float*)d_out;
    float* w_out = out;                                  // NROWS*EEXP floats
    float* pen   = out + (size_t)NROWS * EEXP;           // 1 float

    ushort_t* Wf     = (ushort_t*)d_ws;                  // 131072 ushorts
    int* hist_slices = (int*)(Wf + 131072);              // HB*NDOCS ints
    int* sorted_rows = hist_slices + HB * NDOCS;
    int* offsets     = sorted_rows + NROWS;
    int* cursor      = offsets + NDOCS + 1;
    float* pen_sum   = (float*)(cursor + NDOCS);
    float* uniq      = pen_sum + 1;
    int* done_count  = (int*)(uniq + 1);

    conv_hist_kernel<<<512 + HB, 256, 0, stream>>>(Wg, Wf, idx, hist_slices);
    scan_kernel<<<1, 1024, 0, stream>>>(hist_slices, offsets, cursor, pen_sum, uniq, done_count);
    gemm_scatter_kernel<<<NGEMM + HB, 256, 0, stream>>>(x, Wf, idx, cursor, sorted_rows, w_out);
    segsum_final_kernel<<<NDOCS, 256, 0, stream>>>(w_out, sorted_rows, offsets, pen_sum, uniq, done_count, pen);
}